// Round 1
// baseline (3434.327 us; speedup 1.0000x reference)
//
#include <hip/hip_runtime.h>
#include <math.h>

constexpr int D_TOT = 97;
constexpr int K_POOL = 30;
constexpr float NEG = -3.0e38f;

// ---------------- degree / norm ----------------
__global__ void k_deg(const int* __restrict__ dst, int E, int* __restrict__ deg) {
    int e = blockIdx.x * blockDim.x + threadIdx.x;
    if (e < E) atomicAdd(&deg[dst[e]], 1);
}

__global__ void k_dis(const int* __restrict__ deg, float* __restrict__ dis, int n) {
    int i = blockIdx.x * blockDim.x + threadIdx.x;
    if (i < n) dis[i] = rsqrtf((float)(deg[i] + 1));   // +1 self-loop; always >=1
}

// ---------------- per-layer transform: g[i,c] = dis[i] * (h[i,:] @ W[:,c]) ----------------
template<int FIN, int FOUT>
__global__ void k_transform(const float* __restrict__ h, int ldh,
                            const float* __restrict__ W,
                            const float* __restrict__ dis,
                            float* __restrict__ g, int n) {
    int t = blockIdx.x * blockDim.x + threadIdx.x;
    int i = t / FOUT, c = t % FOUT;
    if (i >= n) return;
    const float* hr = h + (size_t)i * ldh;
    float a = 0.f;
#pragma unroll
    for (int f = 0; f < FIN; ++f) a += hr[f] * W[f * FOUT + c];
    g[(size_t)i * FOUT + c] = dis[i] * a;
}

// ---------------- edge scatter (FOUT=32): 8 threads/edge, float4 each ----------------
__global__ void k_scatter32(const int* __restrict__ src, const int* __restrict__ dst,
                            const float4* __restrict__ g4, float* __restrict__ acc, int E) {
    int t = blockIdx.x * blockDim.x + threadIdx.x;
    int e = t >> 3, p = t & 7;
    if (e >= E) return;
    int s = src[e], d = dst[e];
    float4 v = g4[(size_t)s * 8 + p];
    float* a = acc + (size_t)d * 32 + p * 4;
    atomicAdd(a + 0, v.x);
    atomicAdd(a + 1, v.y);
    atomicAdd(a + 2, v.z);
    atomicAdd(a + 3, v.w);
}

__global__ void k_scatter1(const int* __restrict__ src, const int* __restrict__ dst,
                           const float* __restrict__ g, float* __restrict__ acc, int E) {
    int e = blockIdx.x * blockDim.x + threadIdx.x;
    if (e < E) atomicAdd(&acc[dst[e]], g[src[e]]);
}

// ---------------- finalize: feat[i, off+c] = tanh(dis[i]*(acc+g) + b[c]) ----------------
template<int FOUT>
__global__ void k_finalize(const float* __restrict__ acc, const float* __restrict__ g,
                           const float* __restrict__ dis, const float* __restrict__ b,
                           float* __restrict__ feat, int outoff, int n) {
    int t = blockIdx.x * blockDim.x + threadIdx.x;
    int i = t / FOUT, c = t % FOUT;
    if (i >= n) return;
    float v = dis[i] * (acc[t] + g[t]) + b[c];
    feat[(size_t)i * D_TOT + outoff + c] = tanhf(v);
}

// ---------------- per-graph counts ----------------
__global__ void k_hist(const int* __restrict__ batch, int n, int* __restrict__ counts) {
    int i = blockIdx.x * blockDim.x + threadIdx.x;
    if (i < n) atomicAdd(&counts[batch[i]], 1);
}

__global__ void k_scan(const int* __restrict__ counts, int* __restrict__ starts, int G) {
    __shared__ int s[1024];
    int t = threadIdx.x;
    int mine = (t < G) ? counts[t] : 0;
    s[t] = mine;
    __syncthreads();
    for (int off = 1; off < 1024; off <<= 1) {
        int add = 0;
        if (t >= off) add = s[t - off];
        __syncthreads();
        s[t] += add;
        __syncthreads();
    }
    if (t < G) starts[t] = s[t] - mine;   // exclusive
}

// ---------------- fused sort-pool + conv1 + maxpool + conv2 + MLP, one block/graph ----------------
constexpr int MAXN_G = 1024;

__global__ __launch_bounds__(128) void k_cnn(
    const float* __restrict__ feat,
    const int* __restrict__ starts, const int* __restrict__ counts,
    const float* __restrict__ c1w, const float* __restrict__ c1b,
    const float* __restrict__ c2w, const float* __restrict__ c2b,
    const float* __restrict__ m1w, const float* __restrict__ m1b,
    const float* __restrict__ m2w, const float* __restrict__ m2b,
    float* __restrict__ out)
{
    int g = blockIdx.x;
    int tid = threadIdx.x;

    __shared__ float vals[MAXN_G];
    __shared__ int   sel[K_POOL];
    __shared__ float pooled[K_POOL][D_TOT];
    __shared__ float y[16][K_POOL];
    __shared__ float z[16][15];
    __shared__ float u[352];
    __shared__ float hid[32];
    __shared__ float red[128];
    __shared__ int   redi[128];

    int start = starts[g];
    int cnt = counts[g];
    if (cnt > MAXN_G) cnt = MAXN_G;
    int kk = cnt < K_POOL ? cnt : K_POOL;

    // load last feature per node of this graph
    for (int i = tid; i < cnt; i += 128)
        vals[i] = feat[(size_t)(start + i) * D_TOT + (D_TOT - 1)];
    __syncthreads();

    // iterative top-k selection: value desc, tie -> lower index (stable lexsort semantics)
    for (int k = 0; k < kk; ++k) {
        float bv = NEG; int bi = 0x7fffffff;
        for (int i = tid; i < cnt; i += 128) {
            float v = vals[i];
            if (v > bv || (v == bv && i < bi)) { bv = v; bi = i; }
        }
        red[tid] = bv; redi[tid] = bi;
        __syncthreads();
        for (int s2 = 64; s2 > 0; s2 >>= 1) {
            if (tid < s2) {
                float ov = red[tid + s2]; int oi = redi[tid + s2];
                if (ov > red[tid] || (ov == red[tid] && oi < redi[tid])) {
                    red[tid] = ov; redi[tid] = oi;
                }
            }
            __syncthreads();
        }
        if (tid == 0) { sel[k] = redi[0]; vals[redi[0]] = NEG; }
        __syncthreads();
    }

    // gather pooled rows (zero-pad graphs with < K nodes)
    float* pf = &pooled[0][0];
    for (int t = tid; t < K_POOL * D_TOT; t += 128) pf[t] = 0.f;
    __syncthreads();
    for (int t = tid; t < kk * D_TOT; t += 128) {
        int r = t / D_TOT, c = t - r * D_TOT;
        pf[t] = feat[(size_t)(start + sel[r]) * D_TOT + c];
    }
    __syncthreads();

    // conv1: kernel=stride=97 -> per-row dense 97->16, relu
    for (int t = tid; t < 16 * K_POOL; t += 128) {
        int o = t / K_POOL, p = t - o * K_POOL;
        float a = c1b[o];
        const float* w = c1w + o * D_TOT;
        const float* pr = &pooled[p][0];
#pragma unroll 1
        for (int c = 0; c < D_TOT; ++c) a += pr[c] * w[c];
        y[o][p] = fmaxf(a, 0.f);
    }
    __syncthreads();

    // maxpool window 2 stride 2
    for (int t = tid; t < 16 * 15; t += 128) {
        int o = t / 15, p = t - o * 15;
        z[o][p] = fmaxf(y[o][2 * p], y[o][2 * p + 1]);
    }
    __syncthreads();

    // conv2: 16->32 channels, kernel 5, relu; u layout [q*11+p]
    for (int t = tid; t < 32 * 11; t += 128) {
        int q = t / 11, p = t - q * 11;
        float a = c2b[q];
        const float* w = c2w + q * 16 * 5;
#pragma unroll 1
        for (int c = 0; c < 16; ++c) {
#pragma unroll
            for (int j = 0; j < 5; ++j) a += z[c][p + j] * w[c * 5 + j];
        }
        u[t] = fmaxf(a, 0.f);
    }
    __syncthreads();

    // mlp1: 352 -> 32, relu
    if (tid < 32) {
        float a = m1b[tid];
        for (int i = 0; i < 352; ++i) a += u[i] * m1w[i * 32 + tid];
        hid[tid] = fmaxf(a, 0.f);
    }
    __syncthreads();

    // mlp2: 32 -> 1
    if (tid == 0) {
        float a = m2b[0];
#pragma unroll
        for (int m = 0; m < 32; ++m) a += hid[m] * m2w[m];
        out[g] = a;
    }
}

// ---------------- launch ----------------
extern "C" void kernel_launch(void* const* d_in, const int* in_sizes, int n_in,
                              void* d_out, int out_size, void* d_ws, size_t ws_size,
                              hipStream_t stream) {
    const float* x    = (const float*)d_in[0];
    const int*   ei   = (const int*)d_in[1];
    const int*   batch= (const int*)d_in[2];
    const float* W0   = (const float*)d_in[3];
    const float* b0   = (const float*)d_in[4];
    const float* W1   = (const float*)d_in[5];
    const float* b1   = (const float*)d_in[6];
    const float* W2   = (const float*)d_in[7];
    const float* b2   = (const float*)d_in[8];
    const float* W3   = (const float*)d_in[9];
    const float* b3   = (const float*)d_in[10];
    const float* c1w  = (const float*)d_in[11];
    const float* c1b  = (const float*)d_in[12];
    const float* c2w  = (const float*)d_in[13];
    const float* c2b  = (const float*)d_in[14];
    const float* m1w  = (const float*)d_in[15];
    const float* m1b  = (const float*)d_in[16];
    const float* m2w  = (const float*)d_in[17];
    const float* m2b  = (const float*)d_in[18];

    const int n = in_sizes[0] / 20;
    const int E = in_sizes[1] / 2;
    const int G = out_size;
    const int* srcv = ei;
    const int* dstv = ei + E;

    char* ws = (char*)d_ws;
    float* feat   = (float*)ws;  ws += (size_t)n * D_TOT * sizeof(float);
    float* gbuf   = (float*)ws;  ws += (size_t)n * 32 * sizeof(float);
    float* accb   = (float*)ws;  ws += (size_t)n * 32 * sizeof(float);
    float* dis    = (float*)ws;  ws += (size_t)n * sizeof(float);
    int*   deg    = (int*)ws;    ws += (size_t)n * sizeof(int);
    int*   counts = (int*)ws;    ws += (size_t)G * sizeof(int);
    int*   startsb= (int*)ws;    ws += (size_t)G * sizeof(int);

    hipMemsetAsync(deg, 0, (size_t)n * sizeof(int), stream);
    hipMemsetAsync(counts, 0, (size_t)G * sizeof(int), stream);
    k_deg<<<(E + 255) / 256, 256, 0, stream>>>(dstv, E, deg);
    k_dis<<<(n + 255) / 256, 256, 0, stream>>>(deg, dis, n);
    k_hist<<<(n + 255) / 256, 256, 0, stream>>>(batch, n, counts);
    k_scan<<<1, 1024, 0, stream>>>(counts, startsb, G);

    const int nt32 = n * 32;
    // layer 0: 20 -> 32
    k_transform<20, 32><<<(nt32 + 255) / 256, 256, 0, stream>>>(x, 20, W0, dis, gbuf, n);
    hipMemsetAsync(accb, 0, (size_t)n * 32 * sizeof(float), stream);
    k_scatter32<<<((size_t)E * 8 + 255) / 256, 256, 0, stream>>>(srcv, dstv, (const float4*)gbuf, accb, E);
    k_finalize<32><<<(nt32 + 255) / 256, 256, 0, stream>>>(accb, gbuf, dis, b0, feat, 0, n);
    // layer 1: 32 -> 32 (input: feat cols [0,32))
    k_transform<32, 32><<<(nt32 + 255) / 256, 256, 0, stream>>>(feat + 0, D_TOT, W1, dis, gbuf, n);
    hipMemsetAsync(accb, 0, (size_t)n * 32 * sizeof(float), stream);
    k_scatter32<<<((size_t)E * 8 + 255) / 256, 256, 0, stream>>>(srcv, dstv, (const float4*)gbuf, accb, E);
    k_finalize<32><<<(nt32 + 255) / 256, 256, 0, stream>>>(accb, gbuf, dis, b1, feat, 32, n);
    // layer 2: 32 -> 32 (input: feat cols [32,64))
    k_transform<32, 32><<<(nt32 + 255) / 256, 256, 0, stream>>>(feat + 32, D_TOT, W2, dis, gbuf, n);
    hipMemsetAsync(accb, 0, (size_t)n * 32 * sizeof(float), stream);
    k_scatter32<<<((size_t)E * 8 + 255) / 256, 256, 0, stream>>>(srcv, dstv, (const float4*)gbuf, accb, E);
    k_finalize<32><<<(nt32 + 255) / 256, 256, 0, stream>>>(accb, gbuf, dis, b2, feat, 64, n);
    // layer 3: 32 -> 1 (input: feat cols [64,96))
    k_transform<32, 1><<<(n + 255) / 256, 256, 0, stream>>>(feat + 64, D_TOT, W3, dis, gbuf, n);
    hipMemsetAsync(accb, 0, (size_t)n * sizeof(float), stream);
    k_scatter1<<<(E + 255) / 256, 256, 0, stream>>>(srcv, dstv, gbuf, accb, E);
    k_finalize<1><<<(n + 255) / 256, 256, 0, stream>>>(accb, gbuf, dis, b3, feat, 96, n);

    // fused sort-pool + CNN + MLP
    k_cnn<<<G, 128, 0, stream>>>(feat, startsb, counts,
                                 c1w, c1b, c2w, c2b, m1w, m1b, m2w, m2b,
                                 (float*)d_out);
}

// Round 2
// 862.817 us; speedup vs baseline: 3.9804x; 3.9804x over previous
//
#include <hip/hip_runtime.h>
#include <math.h>

constexpr int D_TOT = 97;
constexpr int K_POOL = 30;
constexpr float NEG = -3.0e38f;

// ---------------- degree ----------------
__global__ void k_deg(const int* __restrict__ dst, int E, int* __restrict__ deg) {
    int e = blockIdx.x * blockDim.x + threadIdx.x;
    if (e < E) atomicAdd(&deg[dst[e]], 1);
}

// ---------------- 2-level exclusive scan of deg -> rowstart ----------------
__global__ void k_scan1(const int* __restrict__ deg, int n,
                        int* __restrict__ rowstart, int* __restrict__ bsum) {
    __shared__ int s[1024];
    int t = threadIdx.x;
    int i = blockIdx.x * 1024 + t;
    int mine = (i < n) ? deg[i] : 0;
    s[t] = mine;
    __syncthreads();
    for (int off = 1; off < 1024; off <<= 1) {
        int add = (t >= off) ? s[t - off] : 0;
        __syncthreads();
        s[t] += add;
        __syncthreads();
    }
    if (i < n) rowstart[i] = s[t] - mine;
    if (t == 1023) bsum[blockIdx.x] = s[1023];
}

__global__ void k_scan2(const int* __restrict__ in, int* __restrict__ outx, int m) {
    __shared__ int s[1024];
    int t = threadIdx.x;
    int mine = (t < m) ? in[t] : 0;
    s[t] = mine;
    __syncthreads();
    for (int off = 1; off < 1024; off <<= 1) {
        int add = (t >= off) ? s[t - off] : 0;
        __syncthreads();
        s[t] += add;
        __syncthreads();
    }
    if (t < m) outx[t] = s[t] - mine;   // exclusive
}

__global__ void k_scan3(int* __restrict__ rowstart, const int* __restrict__ boff,
                        const int* __restrict__ deg, int* __restrict__ cursor,
                        float* __restrict__ dis, int n) {
    int i = blockIdx.x * blockDim.x + threadIdx.x;
    if (i >= n) return;
    int r = rowstart[i] + boff[i >> 10];
    rowstart[i] = r;
    cursor[i] = r;
    dis[i] = rsqrtf((float)(deg[i] + 1));   // +1 self-loop
}

// ---------------- CSR fill (order within a row is arbitrary; sum is order-insensitive up to fp) ----------------
__global__ void k_fill(const int* __restrict__ src, const int* __restrict__ dst, int E,
                       int* __restrict__ cursor, int* __restrict__ ssrc) {
    int e = blockIdx.x * blockDim.x + threadIdx.x;
    if (e >= E) return;
    int pos = atomicAdd(&cursor[dst[e]], 1);
    ssrc[pos] = src[e];
}

// ---------------- per-layer transform: g[i,c] = dis[i] * (h[i,:] @ W[:,c]) ----------------
template<int FIN, int FOUT>
__global__ void k_transform(const float* __restrict__ h, int ldh,
                            const float* __restrict__ W,
                            const float* __restrict__ dis,
                            float* __restrict__ g, int n) {
    int t = blockIdx.x * blockDim.x + threadIdx.x;
    int i = t / FOUT, c = t % FOUT;
    if (i >= n) return;
    const float* hr = h + (size_t)i * ldh;
    float a = 0.f;
#pragma unroll
    for (int f = 0; f < FIN; ++f) a += hr[f] * W[f * FOUT + c];
    g[(size_t)i * FOUT + c] = dis[i] * a;
}

// ---------------- CSR gather + finalize, FOUT=32: 8 lanes/node, float4 each ----------------
__global__ void k_gather32(const int* __restrict__ rowstart, const int* __restrict__ deg,
                           const int* __restrict__ ssrc, const float4* __restrict__ g4,
                           const float* __restrict__ dis, const float* __restrict__ b,
                           float* __restrict__ feat, int off, int n) {
    int t = blockIdx.x * blockDim.x + threadIdx.x;
    int i = t >> 3, p = t & 7;
    if (i >= n) return;
    int r0 = rowstart[i], d = deg[i];
    float4 acc = g4[(size_t)i * 8 + p];   // self-loop term
    for (int j = 0; j < d; ++j) {
        int s = ssrc[r0 + j];
        float4 v = g4[(size_t)s * 8 + p];
        acc.x += v.x; acc.y += v.y; acc.z += v.z; acc.w += v.w;
    }
    float sc = dis[i];
    float* fr = feat + (size_t)i * D_TOT + off + p * 4;
    fr[0] = tanhf(sc * acc.x + b[p * 4 + 0]);
    fr[1] = tanhf(sc * acc.y + b[p * 4 + 1]);
    fr[2] = tanhf(sc * acc.z + b[p * 4 + 2]);
    fr[3] = tanhf(sc * acc.w + b[p * 4 + 3]);
}

// ---------------- CSR gather + finalize, FOUT=1 ----------------
__global__ void k_gather1(const int* __restrict__ rowstart, const int* __restrict__ deg,
                          const int* __restrict__ ssrc, const float* __restrict__ g,
                          const float* __restrict__ dis, const float* __restrict__ b,
                          float* __restrict__ feat, int off, int n) {
    int i = blockIdx.x * blockDim.x + threadIdx.x;
    if (i >= n) return;
    int r0 = rowstart[i], d = deg[i];
    float acc = g[i];
    for (int j = 0; j < d; ++j) acc += g[ssrc[r0 + j]];
    feat[(size_t)i * D_TOT + off] = tanhf(dis[i] * acc + b[0]);
}

// ---------------- per-graph counts ----------------
__global__ void k_hist(const int* __restrict__ batch, int n, int* __restrict__ counts) {
    int i = blockIdx.x * blockDim.x + threadIdx.x;
    if (i < n) atomicAdd(&counts[batch[i]], 1);
}

// ---------------- fused sort-pool + conv1 + maxpool + conv2 + MLP, one block/graph ----------------
constexpr int MAXN_G = 1024;

__global__ __launch_bounds__(128) void k_cnn(
    const float* __restrict__ feat,
    const int* __restrict__ starts, const int* __restrict__ counts,
    const float* __restrict__ c1w, const float* __restrict__ c1b,
    const float* __restrict__ c2w, const float* __restrict__ c2b,
    const float* __restrict__ m1w, const float* __restrict__ m1b,
    const float* __restrict__ m2w, const float* __restrict__ m2b,
    float* __restrict__ out)
{
    int g = blockIdx.x;
    int tid = threadIdx.x;

    __shared__ float vals[MAXN_G];
    __shared__ int   sel[K_POOL];
    __shared__ float pooled[K_POOL][D_TOT];
    __shared__ float y[16][K_POOL];
    __shared__ float z[16][15];
    __shared__ float u[352];
    __shared__ float hid[32];
    __shared__ float red[128];
    __shared__ int   redi[128];

    int start = starts[g];
    int cnt = counts[g];
    if (cnt > MAXN_G) cnt = MAXN_G;
    int kk = cnt < K_POOL ? cnt : K_POOL;

    for (int i = tid; i < cnt; i += 128)
        vals[i] = feat[(size_t)(start + i) * D_TOT + (D_TOT - 1)];
    __syncthreads();

    // iterative top-k selection: value desc, tie -> lower index
    for (int k = 0; k < kk; ++k) {
        float bv = NEG; int bi = 0x7fffffff;
        for (int i = tid; i < cnt; i += 128) {
            float v = vals[i];
            if (v > bv || (v == bv && i < bi)) { bv = v; bi = i; }
        }
        red[tid] = bv; redi[tid] = bi;
        __syncthreads();
        for (int s2 = 64; s2 > 0; s2 >>= 1) {
            if (tid < s2) {
                float ov = red[tid + s2]; int oi = redi[tid + s2];
                if (ov > red[tid] || (ov == red[tid] && oi < redi[tid])) {
                    red[tid] = ov; redi[tid] = oi;
                }
            }
            __syncthreads();
        }
        if (tid == 0) { sel[k] = redi[0]; vals[redi[0]] = NEG; }
        __syncthreads();
    }

    float* pf = &pooled[0][0];
    for (int t = tid; t < K_POOL * D_TOT; t += 128) pf[t] = 0.f;
    __syncthreads();
    for (int t = tid; t < kk * D_TOT; t += 128) {
        int r = t / D_TOT, c = t - r * D_TOT;
        pf[t] = feat[(size_t)(start + sel[r]) * D_TOT + c];
    }
    __syncthreads();

    // conv1: kernel=stride=97 -> per-row dense 97->16, relu
    for (int t = tid; t < 16 * K_POOL; t += 128) {
        int o = t / K_POOL, p = t - o * K_POOL;
        float a = c1b[o];
        const float* w = c1w + o * D_TOT;
        const float* pr = &pooled[p][0];
#pragma unroll 1
        for (int c = 0; c < D_TOT; ++c) a += pr[c] * w[c];
        y[o][p] = fmaxf(a, 0.f);
    }
    __syncthreads();

    for (int t = tid; t < 16 * 15; t += 128) {
        int o = t / 15, p = t - o * 15;
        z[o][p] = fmaxf(y[o][2 * p], y[o][2 * p + 1]);
    }
    __syncthreads();

    // conv2: 16->32 channels, kernel 5, relu
    for (int t = tid; t < 32 * 11; t += 128) {
        int q = t / 11, p = t - q * 11;
        float a = c2b[q];
        const float* w = c2w + q * 16 * 5;
#pragma unroll 1
        for (int c = 0; c < 16; ++c) {
#pragma unroll
            for (int j = 0; j < 5; ++j) a += z[c][p + j] * w[c * 5 + j];
        }
        u[t] = fmaxf(a, 0.f);
    }
    __syncthreads();

    if (tid < 32) {
        float a = m1b[tid];
        for (int i = 0; i < 352; ++i) a += u[i] * m1w[i * 32 + tid];
        hid[tid] = fmaxf(a, 0.f);
    }
    __syncthreads();

    if (tid == 0) {
        float a = m2b[0];
#pragma unroll
        for (int m = 0; m < 32; ++m) a += hid[m] * m2w[m];
        out[g] = a;
    }
}

// ---------------- launch ----------------
extern "C" void kernel_launch(void* const* d_in, const int* in_sizes, int n_in,
                              void* d_out, int out_size, void* d_ws, size_t ws_size,
                              hipStream_t stream) {
    const float* x    = (const float*)d_in[0];
    const int*   ei   = (const int*)d_in[1];
    const int*   batch= (const int*)d_in[2];
    const float* W0   = (const float*)d_in[3];
    const float* b0   = (const float*)d_in[4];
    const float* W1   = (const float*)d_in[5];
    const float* b1   = (const float*)d_in[6];
    const float* W2   = (const float*)d_in[7];
    const float* b2   = (const float*)d_in[8];
    const float* W3   = (const float*)d_in[9];
    const float* b3   = (const float*)d_in[10];
    const float* c1w  = (const float*)d_in[11];
    const float* c1b  = (const float*)d_in[12];
    const float* c2w  = (const float*)d_in[13];
    const float* c2b  = (const float*)d_in[14];
    const float* m1w  = (const float*)d_in[15];
    const float* m1b  = (const float*)d_in[16];
    const float* m2w  = (const float*)d_in[17];
    const float* m2b  = (const float*)d_in[18];

    const int n = in_sizes[0] / 20;
    const int E = in_sizes[1] / 2;
    const int G = out_size;
    const int* srcv = ei;
    const int* dstv = ei + E;
    const int nb = (n + 1023) / 1024;

    char* ws = (char*)d_ws;
    float* feat    = (float*)ws;  ws += (size_t)n * D_TOT * sizeof(float);
    float* gbuf    = (float*)ws;  ws += (size_t)n * 32 * sizeof(float);
    int*   ssrc    = (int*)ws;    ws += (size_t)E * sizeof(int);
    int*   rowstart= (int*)ws;    ws += (size_t)n * sizeof(int);
    int*   cursor  = (int*)ws;    ws += (size_t)n * sizeof(int);
    int*   deg     = (int*)ws;    ws += (size_t)n * sizeof(int);
    float* dis     = (float*)ws;  ws += (size_t)n * sizeof(float);
    int*   bsum    = (int*)ws;    ws += (size_t)nb * sizeof(int);
    int*   boff    = (int*)ws;    ws += (size_t)nb * sizeof(int);
    int*   counts  = (int*)ws;    ws += (size_t)G * sizeof(int);
    int*   startsb = (int*)ws;    ws += (size_t)G * sizeof(int);

    hipMemsetAsync(deg, 0, (size_t)n * sizeof(int), stream);
    hipMemsetAsync(counts, 0, (size_t)G * sizeof(int), stream);

    // CSR build (reused by all 4 layers)
    k_deg<<<(E + 255) / 256, 256, 0, stream>>>(dstv, E, deg);
    k_scan1<<<nb, 1024, 0, stream>>>(deg, n, rowstart, bsum);
    k_scan2<<<1, 1024, 0, stream>>>(bsum, boff, nb);
    k_scan3<<<(n + 255) / 256, 256, 0, stream>>>(rowstart, boff, deg, cursor, dis, n);
    k_fill<<<(E + 255) / 256, 256, 0, stream>>>(srcv, dstv, E, cursor, ssrc);

    // per-graph segments
    k_hist<<<(n + 255) / 256, 256, 0, stream>>>(batch, n, counts);
    k_scan2<<<1, 1024, 0, stream>>>(counts, startsb, G);

    const int nt32 = n * 32;
    const int nt8  = n * 8;
    // layer 0: 20 -> 32
    k_transform<20, 32><<<(nt32 + 255) / 256, 256, 0, stream>>>(x, 20, W0, dis, gbuf, n);
    k_gather32<<<(nt8 + 255) / 256, 256, 0, stream>>>(rowstart, deg, ssrc, (const float4*)gbuf, dis, b0, feat, 0, n);
    // layer 1
    k_transform<32, 32><<<(nt32 + 255) / 256, 256, 0, stream>>>(feat + 0, D_TOT, W1, dis, gbuf, n);
    k_gather32<<<(nt8 + 255) / 256, 256, 0, stream>>>(rowstart, deg, ssrc, (const float4*)gbuf, dis, b1, feat, 32, n);
    // layer 2
    k_transform<32, 32><<<(nt32 + 255) / 256, 256, 0, stream>>>(feat + 32, D_TOT, W2, dis, gbuf, n);
    k_gather32<<<(nt8 + 255) / 256, 256, 0, stream>>>(rowstart, deg, ssrc, (const float4*)gbuf, dis, b2, feat, 64, n);
    // layer 3: 32 -> 1
    k_transform<32, 1><<<(n + 255) / 256, 256, 0, stream>>>(feat + 64, D_TOT, W3, dis, gbuf, n);
    k_gather1<<<(n + 255) / 256, 256, 0, stream>>>(rowstart, deg, ssrc, gbuf, dis, b3, feat, 96, n);

    // fused sort-pool + CNN + MLP
    k_cnn<<<G, 128, 0, stream>>>(feat, startsb, counts,
                                 c1w, c1b, c2w, c2b, m1w, m1b, m2w, m2b,
                                 (float*)d_out);
}